// Round 2
// baseline (870.471 us; speedup 1.0000x reference)
//
#include <hip/hip_runtime.h>
#include <math.h>

#define B_RAYS 16384
#define N_I 128
constexpr float RADIUS_ = 1.3f;
constexpr float STEP_ = 0.0203125f;  // 2*1.3/128, exact in fp32

// ---------------- transpose G: [3][16][256][256] -> [3][256][256][16] ----------------
__global__ __launch_bounds__(256) void k_transposeG(const float* __restrict__ G,
                                                    float* __restrict__ Gt) {
    int pl = blockIdx.x >> 8;
    int y  = blockIdx.x & 255;
    __shared__ float tile[16][257];
    int t = threadIdx.x;
#pragma unroll
    for (int ch = 0; ch < 16; ++ch)
        tile[ch][t] = G[((pl * 16 + ch) * 256 + y) * 256 + t];
    __syncthreads();
    float* dst = Gt + (pl * 256 + y) * 256 * 16;
#pragma unroll
    for (int i = 0; i < 16; ++i) {
        int o = i * 256 + t;           // o = x*16 + ch
        dst[o] = tile[o & 15][o >> 4];
    }
}

// ---------------- transpose F: [32][64][64] -> [64][64][32] ----------------
__global__ __launch_bounds__(256) void k_transposeF(const float* __restrict__ F,
                                                    float* __restrict__ Ft) {
    int y = blockIdx.x;  // 0..63
    __shared__ float tile[32][65];
    int t = threadIdx.x;
#pragma unroll
    for (int i = 0; i < 8; ++i) {
        int o = i * 256 + t;  // ch*64 + x
        tile[o >> 6][o & 63] = F[((o >> 6) * 64 + y) * 64 + (o & 63)];
    }
    __syncthreads();
    float* dst = Ft + y * 64 * 32;
#pragma unroll
    for (int i = 0; i < 8; ++i) {
        int o = i * 256 + t;           // o = x*32 + ch
        dst[o] = tile[o & 31][o >> 5];
    }
}

// ---------------- fused per-sample + composite kernel ----------------
// One wave per ray; lane handles samples 2*lane and 2*lane+1 (static unroll).
__global__ __launch_bounds__(256) void k_fused(
    const float* __restrict__ rays_o, const float* __restrict__ rays_d,
    const float* __restrict__ Gt, const float* __restrict__ Ft,
    const float* __restrict__ sW1, const float* __restrict__ sW2,
    const float* __restrict__ cW1, const float* __restrict__ cW2,
    const float* __restrict__ cW3, float* __restrict__ out) {
    // LDS-staged weights. W1 / colorW1 stored transposed (row j = output column)
    __shared__ float w_s1t[64 * 32];   // [j][k]
    __shared__ float w_s2[64 * 16];    // [j][m] row-major as given
    __shared__ float w_c1t[64 * 32];   // [j][k]; k<16 = SH enc, 16..30 = feat, k==31 zeroed
    __shared__ float w_c2[64 * 64];
    __shared__ float w_c3[64 * 3];
    int tid = threadIdx.x;
    for (int i = tid; i < 2048; i += 256) { float v = sW1[i]; w_s1t[(i & 63) * 32 + (i >> 6)] = v; }
    for (int i = tid; i < 1024; i += 256) w_s2[i] = sW2[i];
    for (int i = tid; i < 1984; i += 256) { float v = cW1[i]; w_c1t[(i & 63) * 32 + (i >> 6)] = v; }
    for (int i = tid; i < 64; i += 256) w_c1t[i * 32 + 31] = 0.f;
    for (int i = tid; i < 4096; i += 256) w_c2[i] = cW2[i];
    if (tid < 192) w_c3[tid] = cW3[tid];
    __syncthreads();

    int lane = tid & 63;
    int ray  = (blockIdx.x << 2) + (tid >> 6);

    // ---- per-ray setup (hoisted) ----
    float ox = rays_o[ray * 3 + 0], oy = rays_o[ray * 3 + 1], oz = rays_o[ray * 3 + 2];
    float rx = rays_d[ray * 3 + 0], ry = rays_d[ray * 3 + 1], rz = rays_d[ray * 3 + 2];
    float nrm = sqrtf(rx * rx + ry * ry + rz * rz);
    float dx = rx / nrm, dy = ry / nrm, dz = rz / nrm;
    float bq = ox * dx + oy * dy + oz * dz;
    float cq = ox * ox + oy * oy + oz * oz - RADIUS_ * RADIUS_;
    float disc = bq * bq - cq;
    float sq = sqrtf(fmaxf(disc, 0.f));
    float tnear = fmaxf(-bq - sq, 0.f);
    float tfar = -bq + sq;

    // ---- SH deg4 encoding (per-ray, direction-only) ----
    float enc[16];
    {
        float x = dx, y = dy, z = dz;
        float xx = x * x, yy = y * y, zz = z * z;
        float xy = x * y, yz = y * z, xz = x * z;
        enc[0] = 0.28209479177387814f;
        enc[1] = -0.48860251190291987f * y;
        enc[2] = 0.48860251190291987f * z;
        enc[3] = -0.48860251190291987f * x;
        enc[4] = 1.0925484305920792f * xy;
        enc[5] = -1.0925484305920792f * yz;
        enc[6] = 0.94617469575756f * zz - 0.31539156525252f;
        enc[7] = -1.0925484305920792f * xz;
        enc[8] = 0.5462742152960396f * (xx - yy);
        enc[9] = 0.5900435899266435f * y * (-3.0f * xx + yy);
        enc[10] = 2.890611442640554f * xy * z;
        enc[11] = 0.4570457994644657f * y * (1.0f - 5.0f * zz);
        enc[12] = 0.3731763325901154f * z * (5.0f * zz - 3.0f);
        enc[13] = 0.4570457994644657f * x * (1.0f - 5.0f * zz);
        enc[14] = 1.445305721320277f * z * (xx - yy);
        enc[15] = 0.5900435899266435f * x * (-xx + 3.0f * yy);
    }

    // ---- two samples per lane: s = 2*lane + u ----
    float4 res[2];
#pragma unroll
    for (int u = 0; u < 2; ++u) {
        int s = (lane << 1) + u;
        float t0 = tnear + (float)s * STEP_;
        float t1 = tnear + (float)(s + 1) * STEP_;
        float tmid = 0.5f * (t0 + t1);
        bool mask = (disc > 0.f) && (tmid <= tfar);
        if (!mask) {
            res[u] = make_float4(0.f, 0.f, 0.f, 0.f);
        } else {
            float px = (ox + dx * tmid) / RADIUS_;
            float py = (oy + dy * tmid) / RADIUS_;
            float pz = (oz + dz * tmid) / RADIUS_;

            // ---- tri-plane bilinear, product over planes ----
            float prod[16];
            float cxs[3] = {px, px, py};
            float cys[3] = {py, pz, pz};
#pragma unroll
            for (int pl = 0; pl < 3; ++pl) {
                float fx = fminf(fmaxf((cxs[pl] + 1.0f) * 0.5f * 255.0f, 0.f), 255.f);
                float fy = fminf(fmaxf((cys[pl] + 1.0f) * 0.5f * 255.0f, 0.f), 255.f);
                float x0f = fminf(floorf(fx), 254.f);
                float y0f = fminf(floorf(fy), 254.f);
                int x0 = (int)x0f, y0 = (int)y0f;
                float wx = fx - x0f, wy = fy - y0f;
                float w00 = (1.f - wx) * (1.f - wy), w01 = wx * (1.f - wy);
                float w10 = (1.f - wx) * wy,        w11 = wx * wy;
                const float* b00 = Gt + ((pl * 256 + y0) * 256 + x0) * 16;
#pragma unroll
                for (int q = 0; q < 4; ++q) {
                    float4 g00 = *(const float4*)(b00 + q * 4);
                    float4 g01 = *(const float4*)(b00 + 16 + q * 4);
                    float4 g10 = *(const float4*)(b00 + 4096 + q * 4);
                    float4 g11 = *(const float4*)(b00 + 4112 + q * 4);
                    float a0 = g00.x * w00 + g01.x * w01 + g10.x * w10 + g11.x * w11;
                    float a1 = g00.y * w00 + g01.y * w01 + g10.y * w10 + g11.y * w11;
                    float a2 = g00.z * w00 + g01.z * w01 + g10.z * w10 + g11.z * w11;
                    float a3 = g00.w * w00 + g01.w * w01 + g10.w * w10 + g11.w * w11;
                    if (pl == 0) {
                        prod[q * 4 + 0] = a0; prod[q * 4 + 1] = a1;
                        prod[q * 4 + 2] = a2; prod[q * 4 + 3] = a3;
                    } else {
                        prod[q * 4 + 0] *= a0; prod[q * 4 + 1] *= a1;
                        prod[q * 4 + 2] *= a2; prod[q * 4 + 3] *= a3;
                    }
                }
            }
            float Gx = prod[0] + prod[1] + prod[2] + prod[3] + prod[4] + prod[5] + prod[6] + prod[7];
            float Gy = prod[8] + prod[9] + prod[10] + prod[11] + prod[12] + prod[13] + prod[14] + prod[15];

            // ---- Fgrid bilinear (32 channels) ----
            float Fv[32];
            {
                float fx = fminf(fmaxf((Gx + 1.0f) * 0.5f * 63.0f, 0.f), 63.f);
                float fy = fminf(fmaxf((Gy + 1.0f) * 0.5f * 63.0f, 0.f), 63.f);
                float x0f = fminf(floorf(fx), 62.f);
                float y0f = fminf(floorf(fy), 62.f);
                int x0 = (int)x0f, y0 = (int)y0f;
                float wx = fx - x0f, wy = fy - y0f;
                float w00 = (1.f - wx) * (1.f - wy), w01 = wx * (1.f - wy);
                float w10 = (1.f - wx) * wy,        w11 = wx * wy;
                const float* f00 = Ft + (y0 * 64 + x0) * 32;
#pragma unroll
                for (int q = 0; q < 8; ++q) {
                    float4 g00 = *(const float4*)(f00 + q * 4);
                    float4 g01 = *(const float4*)(f00 + 32 + q * 4);
                    float4 g10 = *(const float4*)(f00 + 2048 + q * 4);
                    float4 g11 = *(const float4*)(f00 + 2048 + 32 + q * 4);
                    Fv[q * 4 + 0] = g00.x * w00 + g01.x * w01 + g10.x * w10 + g11.x * w11;
                    Fv[q * 4 + 1] = g00.y * w00 + g01.y * w01 + g10.y * w10 + g11.y * w11;
                    Fv[q * 4 + 2] = g00.z * w00 + g01.z * w01 + g10.z * w10 + g11.z * w11;
                    Fv[q * 4 + 3] = g00.w * w00 + g01.w * w01 + g10.w * w10 + g11.w * w11;
                }
            }

            // ---- sigma MLP fused: hh = relu(Fv@W1) @ W2 ----
            float hh[16];
#pragma unroll
            for (int m = 0; m < 16; ++m) hh[m] = 0.f;
            for (int j = 0; j < 64; ++j) {
                const float4* wrow = (const float4*)&w_s1t[j * 32];
                float a0 = 0.f, a1 = 0.f, a2 = 0.f, a3 = 0.f;
#pragma unroll
                for (int q = 0; q < 8; ++q) {
                    float4 w = wrow[q];
                    a0 = fmaf(Fv[q * 4 + 0], w.x, a0);
                    a1 = fmaf(Fv[q * 4 + 1], w.y, a1);
                    a2 = fmaf(Fv[q * 4 + 2], w.z, a2);
                    a3 = fmaf(Fv[q * 4 + 3], w.w, a3);
                }
                float a = fmaxf((a0 + a1) + (a2 + a3), 0.f);
                const float4* w2row = (const float4*)&w_s2[j * 16];
#pragma unroll
                for (int q = 0; q < 4; ++q) {
                    float4 w = w2row[q];
                    hh[q * 4 + 0] = fmaf(a, w.x, hh[q * 4 + 0]);
                    hh[q * 4 + 1] = fmaf(a, w.y, hh[q * 4 + 1]);
                    hh[q * 4 + 2] = fmaf(a, w.z, hh[q * 4 + 2]);
                    hh[q * 4 + 3] = fmaf(a, w.w, hh[q * 4 + 3]);
                }
            }

            // ---- color MLP fused: a_j = relu(enc·W1[0:16,j] + feat·W1[16:31,j]) ----
            // w_c1t row halves: q=0..3 -> enc (k 0..15), q=4..7 -> feat (k 16..31, k==31 zero-wt)
            float c2[64];
#pragma unroll
            for (int m = 0; m < 64; ++m) c2[m] = 0.f;
            for (int j = 0; j < 64; ++j) {
                const float4* wrow = (const float4*)&w_c1t[j * 32];
                float a0 = 0.f, a1 = 0.f, a2 = 0.f, a3 = 0.f;
#pragma unroll
                for (int q = 0; q < 4; ++q) {
                    float4 w = wrow[q];
                    a0 = fmaf(enc[q * 4 + 0], w.x, a0);
                    a1 = fmaf(enc[q * 4 + 1], w.y, a1);
                    a2 = fmaf(enc[q * 4 + 2], w.z, a2);
                    a3 = fmaf(enc[q * 4 + 3], w.w, a3);
                }
#pragma unroll
                for (int q = 0; q < 4; ++q) {
                    float4 w = wrow[4 + q];
                    float e0 = hh[q * 4 + 1];
                    float e1 = hh[q * 4 + 2];
                    float e2 = hh[q * 4 + 3];
                    float e3 = (q == 3) ? 0.f : hh[q * 4 + 4];
                    a0 = fmaf(e0, w.x, a0);
                    a1 = fmaf(e1, w.y, a1);
                    a2 = fmaf(e2, w.z, a2);
                    a3 = fmaf(e3, w.w, a3);
                }
                float a = fmaxf((a0 + a1) + (a2 + a3), 0.f);
                const float4* w2row = (const float4*)&w_c2[j * 64];
#pragma unroll
                for (int q = 0; q < 16; ++q) {
                    float4 w = w2row[q];
                    c2[q * 4 + 0] = fmaf(a, w.x, c2[q * 4 + 0]);
                    c2[q * 4 + 1] = fmaf(a, w.y, c2[q * 4 + 1]);
                    c2[q * 4 + 2] = fmaf(a, w.z, c2[q * 4 + 2]);
                    c2[q * 4 + 3] = fmaf(a, w.w, c2[q * 4 + 3]);
                }
            }
            float col0 = 0.f, col1 = 0.f, col2 = 0.f;
#pragma unroll
            for (int m = 0; m < 64; ++m) {
                float v = fmaxf(c2[m], 0.f);
                col0 = fmaf(v, w_c3[m * 3 + 0], col0);
                col1 = fmaf(v, w_c3[m * 3 + 1], col1);
                col2 = fmaf(v, w_c3[m * 3 + 2], col2);
            }

            float sigma = fmaxf(hh[0], 0.f);
            float r = 1.f / (1.f + expf(-col0));
            float g = 1.f / (1.f + expf(-col1));
            float b = 1.f / (1.f + expf(-col2));
            res[u] = make_float4(sigma, r, g, b);
        }
    }

    // ---- composite (per-wave scan; identical math to reference cumprod) ----
    int s0 = lane * 2;
    float4 p0 = res[0];
    float4 p1 = res[1];
    float ta = tnear + (float)s0 * STEP_;
    float tb = tnear + (float)(s0 + 1) * STEP_;
    float tc = tnear + (float)(s0 + 2) * STEP_;
    float d0 = tb - ta, d1 = tc - tb;
    float alpha0 = 1.f - expf(-p0.x * d0);
    float alpha1 = 1.f - expf(-p1.x * d1);
    float f0 = (1.f - alpha0) + 1e-10f;
    float f1 = (1.f - alpha1) + 1e-10f;
    float fp = f0 * f1;

    float P = fp;  // inclusive prefix product of lane-pair products
#pragma unroll
    for (int dlt = 1; dlt < 64; dlt <<= 1) {
        float v = __shfl_up(P, dlt, 64);
        if (lane >= dlt) P *= v;
    }
    float E = __shfl_up(P, 1, 64);  // exclusive
    if (lane == 0) E = 1.f;

    float w0 = alpha0 * E;
    float w1 = alpha1 * (E * f0);
    float sr = w0 * p0.y + w1 * p1.y;
    float sg = w0 * p0.z + w1 * p1.z;
    float sb = w0 * p0.w + w1 * p1.w;
    float sa = w0 + w1;
#pragma unroll
    for (int m = 32; m >= 1; m >>= 1) {
        sr += __shfl_xor(sr, m, 64);
        sg += __shfl_xor(sg, m, 64);
        sb += __shfl_xor(sb, m, 64);
        sa += __shfl_xor(sa, m, 64);
    }
    if (lane == 0) {
        float bg = 1.f - sa;
        out[ray * 3 + 0] = sr + bg;
        out[ray * 3 + 1] = sg + bg;
        out[ray * 3 + 2] = sb + bg;
    }
}

extern "C" void kernel_launch(void* const* d_in, const int* in_sizes, int n_in,
                              void* d_out, int out_size, void* d_ws, size_t ws_size,
                              hipStream_t stream) {
    const float* rays_o = (const float*)d_in[0];
    const float* rays_d = (const float*)d_in[1];
    const float* G      = (const float*)d_in[2];
    const float* Fgrid  = (const float*)d_in[3];
    const float* sW1    = (const float*)d_in[4];
    const float* sW2    = (const float*)d_in[5];
    const float* cW1    = (const float*)d_in[6];
    const float* cW2    = (const float*)d_in[7];
    const float* cW3    = (const float*)d_in[8];
    float* out = (float*)d_out;

    char* ws = (char*)d_ws;
    float* Gt = (float*)ws;                  // 12,582,912 B
    float* Ft = (float*)(ws + 12582912);     //    524,288 B  (total 13.1 MB)

    k_transposeG<<<768, 256, 0, stream>>>(G, Gt);
    k_transposeF<<<64, 256, 0, stream>>>(Fgrid, Ft);
    k_fused<<<B_RAYS / 4, 256, 0, stream>>>(
        rays_o, rays_d, Gt, Ft, sW1, sW2, cW1, cW2, cW3, out);
}